// Round 4
// baseline (2346.474 us; speedup 1.0000x reference)
//
#include <hip/hip_runtime.h>
#include <math.h>

// ---------------- problem constants ----------------
#define DD 768
#define NHEAD 12
#define HDIM 64
#define NTOK 197
#define BB 8
#define TT (BB*NTOK)          // 1576 tokens
#define NPATCH 196
#define TP (BB*NPATCH)        // 1568 patch rows
#define HID 3072
#define NEXP 8
#define NCLS 1000
#define QKVN (3*DD)           // 2304
#define MAXA 4224             // 33*128 padded MoE capacity (2*TT + 8*127 = 4168)
#define NAT 33                // MoE row tiles of 128
#define NCH 7                 // attention: 7 chunks of 32 cols (224 >= 197)

// epilogue flags
#define F_BIAS    1
#define F_GELU    2
#define F_RESID   4
#define F_OUTBF   8
#define F_MOE     16
#define F_GATHER  32
#define F_SCATTER 64

typedef __bf16 bf16_t;
typedef __attribute__((ext_vector_type(8))) __bf16 bf16x8;
typedef __attribute__((ext_vector_type(4))) float f32x4;

__device__ __forceinline__ float gelu_f(float x) {
  return 0.5f * x * (1.0f + erff(x * 0.70710678118654752f));
}

// ---------------- transpose+cast: src fp32 [K][N] -> dst bf16 [N][K] ----------------
__global__ void tcast_k(const float* __restrict__ src, bf16_t* __restrict__ dst,
                        int K, int N) {
  src += (size_t)blockIdx.z * K * N;
  dst += (size_t)blockIdx.z * K * N;
  __shared__ float t[32][33];
  int n0 = blockIdx.x * 32, k0 = blockIdx.y * 32;
  int tx = threadIdx.x, ty = threadIdx.y;      // 32 x 8
  #pragma unroll
  for (int i = 0; i < 4; i++)
    t[ty + i*8][tx] = src[(size_t)(k0 + ty + i*8) * N + n0 + tx];
  __syncthreads();
  #pragma unroll
  for (int i = 0; i < 4; i++)
    dst[(size_t)(n0 + ty + i*8) * K + k0 + tx] = (bf16_t)t[tx][ty + i*8];
}

// ---------------- patchify: x[B,3,224,224] -> pm_bf[1568,768] bf16 ----------------
__global__ void patchify_k(const float* __restrict__ x, bf16_t* __restrict__ pm) {
  int idx = blockIdx.x * 256 + threadIdx.x;
  if (idx >= TP * DD) return;
  int cidx = idx % DD;
  int row  = idx / DD;
  int b = row / NPATCH, p = row % NPATCH;
  int c = cidx >> 8;
  int rem = cidx & 255;
  int i = rem >> 4, j = rem & 15;
  int gy = p / 14, gx = p % 14;
  pm[idx] = (bf16_t)x[((size_t)(b*3 + c)*224 + gy*16 + i)*224 + gx*16 + j];
}

// ---------------- assemble h (fp32): cls+pos / tok+pos ----------------
__global__ void assemble_k(const float* __restrict__ tok, const float* __restrict__ cls,
                           const float* __restrict__ pos, float* __restrict__ h) {
  int idx = blockIdx.x * 256 + threadIdx.x;
  if (idx >= TT * DD) return;
  int c = idx % DD;
  int row = idx / DD;
  int b = row / NTOK, n = row % NTOK;
  float v;
  if (n == 0) v = cls[c] + pos[c];
  else        v = tok[((size_t)(b*NPATCH + n - 1))*DD + c] + pos[(size_t)n*DD + c];
  h[idx] = v;
}

// ---------------- layernorm (dual fp32 + optional bf16 out) ----------------
__global__ void ln_k(const float* __restrict__ in, size_t in_stride,
                     const float* __restrict__ g, const float* __restrict__ bta,
                     float* __restrict__ out, bf16_t* __restrict__ out_bf, int nrows) {
  int r = blockIdx.x;
  if (r >= nrows) return;
  const float* xr = in + (size_t)r * in_stride;
  __shared__ float red[256];
  int tid = threadIdx.x;
  float v0 = xr[tid], v1 = xr[tid+256], v2 = xr[tid+512];
  red[tid] = v0 + v1 + v2; __syncthreads();
  for (int st = 128; st > 0; st >>= 1) { if (tid < st) red[tid] += red[tid+st]; __syncthreads(); }
  float mean = red[0] * (1.0f/768.0f); __syncthreads();
  float d0 = v0-mean, d1 = v1-mean, d2 = v2-mean;
  red[tid] = d0*d0 + d1*d1 + d2*d2; __syncthreads();
  for (int st = 128; st > 0; st >>= 1) { if (tid < st) red[tid] += red[tid+st]; __syncthreads(); }
  float rstd = rsqrtf(red[0] * (1.0f/768.0f) + 1e-5f);
  float o0 = d0*rstd*g[tid]     + bta[tid];
  float o1 = d1*rstd*g[tid+256] + bta[tid+256];
  float o2 = d2*rstd*g[tid+512] + bta[tid+512];
  float* o = out + (size_t)r * DD;
  o[tid] = o0; o[tid+256] = o1; o[tid+512] = o2;
  if (out_bf) {
    bf16_t* ob = out_bf + (size_t)r * DD;
    ob[tid] = (bf16_t)o0; ob[tid+256] = (bf16_t)o1; ob[tid+512] = (bf16_t)o2;
  }
}

// ---------------- pipelined MFMA GEMM: C[M,N] = epi(A[M,K] @ Bt[N,K]^T) ----------------
// Tile 128 x BN, BK=64 (two 32-halves in LDS). Register-prefetch pipeline:
//   preload k0 -> loop { sync; LDS<-regs; sync; issue loads k0+64; ds_read+MFMA }
// BN=128: 4 waves in 2x2, acc 4x4. BN=64: 4 waves in 4x1, acc 2x4.
template<int BN>
__global__ __launch_bounds__(256) void mgemm_t(
    const bf16_t* __restrict__ A, const bf16_t* __restrict__ Bt,
    const float* __restrict__ bias, const float* __restrict__ resid,
    float* __restrict__ Cf, bf16_t* __restrict__ Cb,
    int M, int N, int K, int flags,
    const int* __restrict__ offs, const int* __restrict__ cnt,
    const int* __restrict__ tok_l, const int* __restrict__ slot_l,
    const float* __restrict__ gate_l, float* __restrict__ scat_out) {
  constexpr int NB = (BN == 128) ? 2 : 1;   // B row-blocks staged per wave
  constexpr int MI = (BN == 128) ? 4 : 2;   // m-frags per wave
  constexpr int NJ = 4;                     // n-frags per wave
  int row0 = blockIdx.y << 7;
  int col0 = blockIdx.x * BN;
  int vend = M;
  const bf16_t* bt = Bt;
  const float* bs = bias;
  if (flags & F_MOE) {
    int total = offs[NEXP];
    if (row0 >= total) return;
    int e = 0;
    #pragma unroll
    for (int q = 1; q < NEXP; q++) if (row0 >= offs[q]) e = q;
    vend = offs[e] + cnt[e];
    bt = Bt + (size_t)e * N * K;
    bs = bias ? bias + (size_t)e * N : bias;
  }
  int tid = threadIdx.x, wave = tid >> 6, lane = tid & 63;
  int r16 = lane & 15, kq = lane >> 4;
  int kq8 = kq << 3;
  __shared__ bf16_t As[2][128*32];
  __shared__ bf16_t Bs[2][BN*32];
  const bf16_t* aptr[2];
  const bf16_t* bptr[NB];
  #pragma unroll
  for (int s = 0; s < 2; s++) {
    int rl = ((wave*2 + s) << 4) + r16;
    int gr = row0 + rl;
    if (flags & F_GATHER) {
      int t = (gr < vend) ? tok_l[gr] : 0;
      aptr[s] = A + (size_t)t * K;
    } else {
      int cr = gr; if (cr > vend - 1) cr = vend - 1;
      aptr[s] = A + (size_t)cr * K;
    }
  }
  #pragma unroll
  for (int s = 0; s < NB; s++) {
    int rl = ((wave*NB + s) << 4) + r16;
    bptr[s] = bt + (size_t)(col0 + rl) * K;
  }
  int woffA = wave*1024 + lane*8;
  int woffB = wave*NB*512 + lane*8;
  int mi0 = (BN == 128) ? ((wave >> 1) * 4) : (wave * 2);
  int ni0 = (BN == 128) ? ((wave & 1) * 4) : 0;

  f32x4 acc[MI][NJ];
  #pragma unroll
  for (int i = 0; i < MI; i++)
    #pragma unroll
    for (int j = 0; j < NJ; j++)
      acc[i][j] = (f32x4){0.f, 0.f, 0.f, 0.f};

  uint4 pa[2][2], pb[NB][2];
  #pragma unroll
  for (int s = 0; s < 2; s++)
    #pragma unroll
    for (int hh2 = 0; hh2 < 2; hh2++)
      pa[s][hh2] = *(const uint4*)(aptr[s] + hh2*32 + kq8);
  #pragma unroll
  for (int s = 0; s < NB; s++)
    #pragma unroll
    for (int hh2 = 0; hh2 < 2; hh2++)
      pb[s][hh2] = *(const uint4*)(bptr[s] + hh2*32 + kq8);

  for (int k0 = 0; k0 < K; k0 += 64) {
    __syncthreads();
    #pragma unroll
    for (int hh2 = 0; hh2 < 2; hh2++) {
      *(uint4*)&As[hh2][woffA]       = pa[0][hh2];
      *(uint4*)&As[hh2][woffA + 512] = pa[1][hh2];
      *(uint4*)&Bs[hh2][woffB]       = pb[0][hh2];
      if (NB == 2) *(uint4*)&Bs[hh2][woffB + 512] = pb[1][hh2];
    }
    __syncthreads();
    int kn = (k0 + 64 < K) ? (k0 + 64) : 0;   // last iter: dummy reload
    #pragma unroll
    for (int s = 0; s < 2; s++)
      #pragma unroll
      for (int hh2 = 0; hh2 < 2; hh2++)
        pa[s][hh2] = *(const uint4*)(aptr[s] + kn + hh2*32 + kq8);
    #pragma unroll
    for (int s = 0; s < NB; s++)
      #pragma unroll
      for (int hh2 = 0; hh2 < 2; hh2++)
        pb[s][hh2] = *(const uint4*)(bptr[s] + kn + hh2*32 + kq8);
    #pragma unroll
    for (int hh2 = 0; hh2 < 2; hh2++) {
      bf16x8 af[MI], bfr[NJ];
      #pragma unroll
      for (int i = 0; i < MI; i++) af[i]  = *(const bf16x8*)&As[hh2][(mi0+i)*512 + lane*8];
      #pragma unroll
      for (int j = 0; j < NJ; j++) bfr[j] = *(const bf16x8*)&Bs[hh2][(ni0+j)*512 + lane*8];
      #pragma unroll
      for (int i = 0; i < MI; i++)
        #pragma unroll
        for (int j = 0; j < NJ; j++)
          acc[i][j] = __builtin_amdgcn_mfma_f32_16x16x32_bf16(af[i], bfr[j], acc[i][j], 0, 0, 0);
    }
  }

  int rq = kq << 2;
  #pragma unroll
  for (int i = 0; i < MI; i++) {
    #pragma unroll
    for (int p = 0; p < 4; p++) {
      int rr = row0 + ((mi0 + i) << 4) + rq + p;
      if (rr >= vend) continue;
      int t = 0, sl = 0; float gv = 0.f;
      if (flags & F_SCATTER) { t = tok_l[rr]; sl = slot_l[rr]; gv = gate_l[rr]; }
      #pragma unroll
      for (int j = 0; j < NJ; j++) {
        int cc = col0 + ((ni0 + j) << 4) + r16;
        float v = acc[i][j][p];
        if (flags & F_BIAS) v += bs[cc];
        if (flags & F_GELU) v = gelu_f(v);
        if (flags & F_SCATTER) {
          scat_out[((size_t)t*2 + sl)*N + cc] = gv * v;
        } else if (flags & F_RESID) {
          Cf[(size_t)rr*N + cc] = v + resid[(size_t)rr*N + cc];
        } else if (flags & F_OUTBF) {
          Cb[(size_t)rr*N + cc] = (bf16_t)v;
        } else {
          Cf[(size_t)rr*N + cc] = v;
        }
      }
    }
  }
}

// ---------------- flash attention: block = (qtile of 64 rows) x (b*head) ----------------
__global__ __launch_bounds__(256) void fattn_k(const bf16_t* __restrict__ qkv,
                                               bf16_t* __restrict__ out) {
  int qt = blockIdx.x;
  int bh = blockIdx.y;
  int b = bh / NHEAD, hh = bh % NHEAD;
  const bf16_t* base = qkv + (size_t)b * NTOK * QKVN;
  int tid = threadIdx.x, wave = tid >> 6, lane = tid & 63;
  int r16 = lane & 15, kq = lane >> 4;

  __shared__ bf16_t Vt[64 * 232];            // V^T [hd][seq], stride 232
  __shared__ bf16_t Ps[4][16 * 40];          // per-wave P scratch, stride 40

  for (int it = 0; it < 56; it++) {
    int idx = it * 256 + tid;
    int d = idx & 63, n = idx >> 6;
    bf16_t bv = (bf16_t)0.f;
    if (n < NTOK) bv = base[(size_t)n * QKVN + 2*DD + hh*HDIM + d];
    Vt[d * 232 + n] = bv;
  }
  __syncthreads();

  int q0 = qt * 64;
  int qrow = q0 + wave * 16 + r16;
  int qr = (qrow < NTOK) ? qrow : 0;
  bf16x8 qf[2];
  #pragma unroll
  for (int ks = 0; ks < 2; ks++)
    qf[ks] = *(const bf16x8*)(base + (size_t)qr * QKVN + hh*HDIM + ks*32 + kq*8);

  f32x4 Oa[4];
  #pragma unroll
  for (int j = 0; j < 4; j++) Oa[j] = (f32x4){0.f,0.f,0.f,0.f};
  float mI[4], lI[4];
  #pragma unroll
  for (int p = 0; p < 4; p++) { mI[p] = -1e30f; lI[p] = 0.f; }

  const bf16_t* Kbase = base + DD + hh*HDIM;
  const bf16x8 zz = {};

  for (int c = 0; c < NCH; c++) {
    f32x4 sc[2];
    sc[0] = (f32x4){0.f,0.f,0.f,0.f};
    sc[1] = (f32x4){0.f,0.f,0.f,0.f};
    #pragma unroll
    for (int tt = 0; tt < 2; tt++) {
      int n = c*32 + tt*16 + r16;
      bool nv = (n < NTOK);
      #pragma unroll
      for (int ks = 0; ks < 2; ks++) {
        bf16x8 kf = zz;
        if (nv) kf = *(const bf16x8*)(Kbase + (size_t)n * QKVN + ks*32 + kq*8);
        sc[tt] = __builtin_amdgcn_mfma_f32_16x16x32_bf16(qf[ks], kf, sc[tt], 0, 0, 0);
      }
    }
    float cm[4];
    #pragma unroll
    for (int p = 0; p < 4; p++) {
      #pragma unroll
      for (int tt = 0; tt < 2; tt++) {
        int col = c*32 + tt*16 + r16;
        float s = sc[tt][p] * 0.125f;
        sc[tt][p] = (col < NTOK) ? s : -1e30f;
      }
      cm[p] = fmaxf(sc[0][p], sc[1][p]);
    }
    #pragma unroll
    for (int off = 1; off < 16; off <<= 1)
      #pragma unroll
      for (int p = 0; p < 4; p++)
        cm[p] = fmaxf(cm[p], __shfl_xor(cm[p], off, 64));
    float al[4], cs[4];
    #pragma unroll
    for (int p = 0; p < 4; p++) {
      float mn = fmaxf(mI[p], cm[p]);
      al[p] = __expf(mI[p] - mn);
      mI[p] = mn;
      float e0 = __expf(sc[0][p] - mn);
      float e1 = __expf(sc[1][p] - mn);
      sc[0][p] = e0; sc[1][p] = e1;
      cs[p] = e0 + e1;
    }
    #pragma unroll
    for (int off = 1; off < 16; off <<= 1)
      #pragma unroll
      for (int p = 0; p < 4; p++)
        cs[p] += __shfl_xor(cs[p], off, 64);
    #pragma unroll
    for (int p = 0; p < 4; p++) lI[p] = lI[p]*al[p] + cs[p];
    #pragma unroll
    for (int j = 0; j < 4; j++)
      #pragma unroll
      for (int p = 0; p < 4; p++)
        Oa[j][p] *= al[p];
    bf16_t* pw = &Ps[wave][0];
    #pragma unroll
    for (int tt = 0; tt < 2; tt++)
      #pragma unroll
      for (int p = 0; p < 4; p++)
        pw[(kq*4+p)*40 + tt*16 + r16] = (bf16_t)sc[tt][p];
    bf16x8 pf = *(const bf16x8*)(pw + r16*40 + kq*8);
    #pragma unroll
    for (int j = 0; j < 4; j++) {
      bf16x8 vf = *(const bf16x8*)(&Vt[(j*16 + r16)*232 + c*32 + kq*8]);
      Oa[j] = __builtin_amdgcn_mfma_f32_16x16x32_bf16(pf, vf, Oa[j], 0, 0, 0);
    }
  }

  #pragma unroll
  for (int p = 0; p < 4; p++) {
    int row = q0 + wave*16 + kq*4 + p;
    if (row >= NTOK) continue;
    float inv = 1.0f / lI[p];
    #pragma unroll
    for (int j = 0; j < 4; j++)
      out[((size_t)b*NTOK + row)*DD + hh*HDIM + j*16 + r16] = (bf16_t)(Oa[j][p] * inv);
  }
}

// ---------------- MoE routing (fp32 gate path) ----------------
__global__ void zero_k(int* __restrict__ cnt) {
  if (threadIdx.x < 16) cnt[threadIdx.x] = 0;
}

__global__ void gate_k(const float* __restrict__ xln, const float* __restrict__ wg,
                       int* __restrict__ e01, float* __restrict__ g01, int* __restrict__ cnt) {
  int t = blockIdx.x * 64 + threadIdx.x;
  if (t >= TT) return;
  float lg[NEXP] = {};
  const float* xr = xln + (size_t)t * DD;
  for (int k = 0; k < DD; k++) {
    float xv = xr[k];
    const float* wr = wg + (size_t)k * NEXP;
    #pragma unroll
    for (int e = 0; e < NEXP; e++) lg[e] += xv * wr[e];
  }
  int e0 = 0; float v0 = lg[0];
  #pragma unroll
  for (int e = 1; e < NEXP; e++) if (lg[e] > v0) { v0 = lg[e]; e0 = e; }
  int e1 = -1; float v1 = -1e30f;
  #pragma unroll
  for (int e = 0; e < NEXP; e++) if (e != e0 && lg[e] > v1) { v1 = lg[e]; e1 = e; }
  float g0 = 1.0f / (1.0f + expf(v1 - v0));
  float g1 = 1.0f - g0;
  e01[t*2]   = e0; e01[t*2+1] = e1;
  g01[t*2]   = g0; g01[t*2+1] = g1;
  atomicAdd(&cnt[e0], 1);
  atomicAdd(&cnt[e1], 1);
}

__global__ void offs_k(const int* __restrict__ cnt, int* __restrict__ offs) {
  if (threadIdx.x == 0 && blockIdx.x == 0) {
    int acc = 0;
    for (int e = 0; e < NEXP; e++) {
      offs[e] = acc;
      acc += ((cnt[e] + 127) >> 7) << 7;
    }
    offs[NEXP] = acc;
  }
}

__global__ void scatter_k(const int* __restrict__ e01, const float* __restrict__ g01,
                          const int* __restrict__ offs, int* __restrict__ cnt2,
                          int* __restrict__ tok_l, float* __restrict__ gate_l,
                          int* __restrict__ slot_l) {
  int t = blockIdx.x * 64 + threadIdx.x;
  if (t >= TT) return;
  #pragma unroll
  for (int s = 0; s < 2; s++) {
    int e = e01[t*2+s];
    int pos = atomicAdd(&cnt2[e], 1);
    int a = offs[e] + pos;
    tok_l[a] = t;
    gate_l[a] = g01[t*2+s];
    slot_l[a] = s;
  }
}

__global__ void combine_k(const float* __restrict__ moe_out, float* __restrict__ h) {
  int idx = blockIdx.x * 256 + threadIdx.x;
  if (idx >= TT * DD) return;
  int c = idx % DD;
  int row = idx / DD;
  h[idx] += moe_out[((size_t)row*2)*DD + c] + moe_out[((size_t)row*2 + 1)*DD + c];
}

// ---------------- head (fp32, small) ----------------
__global__ void head_k(const float* __restrict__ clsln, const float* __restrict__ w_head,
                       const float* __restrict__ b_head, float* __restrict__ out) {
  int id = blockIdx.x * 256 + threadIdx.x;
  if (id >= BB * NCLS) return;
  int b = id / NCLS, c = id % NCLS;
  float acc = b_head[c];
  const float* xr = clsln + (size_t)b * DD;
  for (int k = 0; k < DD; k++) acc += xr[k] * w_head[(size_t)k*NCLS + c];
  out[id] = acc;
}

// ---------------- host ----------------
extern "C" void kernel_launch(void* const* d_in, const int* in_sizes, int n_in,
                              void* d_out, int out_size, void* d_ws, size_t ws_size,
                              hipStream_t stream) {
  const float* x        = (const float*)d_in[0];
  const float* w_patch  = (const float*)d_in[1];
  const float* b_patch  = (const float*)d_in[2];
  const float* cls_tok  = (const float*)d_in[3];
  const float* pos_emb  = (const float*)d_in[4];
  const float* ln1_g    = (const float*)d_in[5];
  const float* ln1_b    = (const float*)d_in[6];
  const float* w_qkv    = (const float*)d_in[7];
  const float* w_proj   = (const float*)d_in[8];
  const float* b_proj   = (const float*)d_in[9];
  const float* ln2_g    = (const float*)d_in[10];
  const float* ln2_b    = (const float*)d_in[11];
  const float* w_fc1    = (const float*)d_in[12];
  const float* b_fc1    = (const float*)d_in[13];
  const float* w_fc2    = (const float*)d_in[14];
  const float* b_fc2    = (const float*)d_in[15];
  const float* w_gate   = (const float*)d_in[16];
  const float* w_e1     = (const float*)d_in[17];
  const float* b_e1     = (const float*)d_in[18];
  const float* w_e2     = (const float*)d_in[19];
  const float* b_e2     = (const float*)d_in[20];
  const float* ln_f_g   = (const float*)d_in[21];
  const float* ln_f_b   = (const float*)d_in[22];
  const float* w_head   = (const float*)d_in[23];
  const float* b_head   = (const float*)d_in[24];
  float* out = (float*)d_out;
  (void)in_sizes; (void)n_in; (void)out_size; (void)ws_size;

  // ---- workspace layout ----
  float* fp = (float*)d_ws;
  float* h      = fp;                          fp += (size_t)TT*DD;
  float* xln    = fp;                          fp += (size_t)TT*DD;
  float* moeout = fp;                          fp += (size_t)TT*2*DD;
  float* clsln  = fp;                          fp += (size_t)8*DD;
  float* g01    = fp;                          fp += (size_t)TT*2;
  float* gate_l = fp;                          fp += (size_t)MAXA;
  int* ip = (int*)fp;
  int* e01    = ip;                            ip += TT*2;
  int* cnt    = ip;                            ip += 8;
  int* cnt2   = ip;                            ip += 8;
  int* offs   = ip;                            ip += 16;
  int* tok_l  = ip;                            ip += MAXA;
  int* slot_l = ip;                            ip += MAXA;
  bf16_t* bp = (bf16_t*)ip;
  bf16_t* pm_bf   = bp;                        bp += (size_t)TP*DD;
  bf16_t* xln_bf  = bp;                        bp += (size_t)TT*DD;
  bf16_t* qkv_bf  = bp;                        bp += (size_t)TT*QKVN;
  bf16_t* attnb   = bp;                        bp += (size_t)TT*DD;
  bf16_t* hid     = bp;                        bp += (size_t)MAXA*HID;
  bf16_t* wT_patch= bp;                        bp += (size_t)DD*DD;
  bf16_t* wT_qkv  = bp;                        bp += (size_t)DD*QKVN;
  bf16_t* wT_proj = bp;                        bp += (size_t)DD*DD;
  bf16_t* wT_big  = bp;                        bp += (size_t)NEXP*DD*HID;

  // ---- patch embedding ----
  tcast_k<<<dim3(DD/32, DD/32, 1), dim3(32,8), 0, stream>>>(w_patch, wT_patch, DD, DD);
  patchify_k<<<(TP*DD + 255)/256, 256, 0, stream>>>(x, pm_bf);
  mgemm_t<64><<<dim3(DD/64, (TP+127)/128), 256, 0, stream>>>(
      pm_bf, wT_patch, b_patch, nullptr, xln, nullptr, TP, DD, DD, F_BIAS,
      nullptr, nullptr, nullptr, nullptr, nullptr, nullptr);
  assemble_k<<<(TT*DD + 255)/256, 256, 0, stream>>>(xln, cls_tok, pos_emb, h);

  const int MT = (TT + 127) / 128;   // 13 row tiles
  for (int i = 0; i < 4; i++) {
    int j = i >> 1;
    // attention
    tcast_k<<<dim3(QKVN/32, DD/32, 1), dim3(32,8), 0, stream>>>(
        w_qkv + (size_t)i*DD*QKVN, wT_qkv, DD, QKVN);
    tcast_k<<<dim3(DD/32, DD/32, 1), dim3(32,8), 0, stream>>>(
        w_proj + (size_t)i*DD*DD, wT_proj, DD, DD);
    ln_k<<<TT, 256, 0, stream>>>(h, DD, ln1_g + (size_t)i*DD, ln1_b + (size_t)i*DD,
                                 xln, xln_bf, TT);
    mgemm_t<128><<<dim3(QKVN/128, MT), 256, 0, stream>>>(
        xln_bf, wT_qkv, nullptr, nullptr, nullptr, qkv_bf, TT, QKVN, DD, F_OUTBF,
        nullptr, nullptr, nullptr, nullptr, nullptr, nullptr);
    fattn_k<<<dim3(4, BB*NHEAD), 256, 0, stream>>>(qkv_bf, attnb);
    mgemm_t<64><<<dim3(DD/64, MT), 256, 0, stream>>>(
        attnb, wT_proj, b_proj + (size_t)i*DD, h, h, nullptr, TT, DD, DD,
        F_BIAS | F_RESID, nullptr, nullptr, nullptr, nullptr, nullptr, nullptr);
    // mlp / moe
    ln_k<<<TT, 256, 0, stream>>>(h, DD, ln2_g + (size_t)i*DD, ln2_b + (size_t)i*DD,
                                 xln, xln_bf, TT);
    if ((i & 1) == 0) {
      tcast_k<<<dim3(HID/32, DD/32, 1), dim3(32,8), 0, stream>>>(
          w_fc1 + (size_t)j*DD*HID, wT_big, DD, HID);
      mgemm_t<128><<<dim3(HID/128, MT), 256, 0, stream>>>(
          xln_bf, wT_big, b_fc1 + (size_t)j*HID, nullptr, nullptr, hid,
          TT, HID, DD, F_BIAS | F_GELU | F_OUTBF,
          nullptr, nullptr, nullptr, nullptr, nullptr, nullptr);
      tcast_k<<<dim3(DD/32, HID/32, 1), dim3(32,8), 0, stream>>>(
          w_fc2 + (size_t)j*HID*DD, wT_big, HID, DD);
      mgemm_t<64><<<dim3(DD/64, MT), 256, 0, stream>>>(
          hid, wT_big, b_fc2 + (size_t)j*DD, h, h, nullptr, TT, DD, HID,
          F_BIAS | F_RESID, nullptr, nullptr, nullptr, nullptr, nullptr, nullptr);
    } else {
      zero_k<<<1, 64, 0, stream>>>(cnt);
      gate_k<<<(TT+63)/64, 64, 0, stream>>>(xln, w_gate + (size_t)j*DD*NEXP, e01, g01, cnt);
      offs_k<<<1, 32, 0, stream>>>(cnt, offs);
      scatter_k<<<(TT+63)/64, 64, 0, stream>>>(e01, g01, offs, cnt2, tok_l, gate_l, slot_l);
      tcast_k<<<dim3(HID/32, DD/32, NEXP), dim3(32,8), 0, stream>>>(
          w_e1 + (size_t)j*NEXP*DD*HID, wT_big, DD, HID);
      mgemm_t<128><<<dim3(HID/128, NAT), 256, 0, stream>>>(
          xln_bf, wT_big, b_e1 + (size_t)j*NEXP*HID, nullptr, nullptr, hid,
          0, HID, DD, F_MOE | F_GATHER | F_BIAS | F_GELU | F_OUTBF,
          offs, cnt, tok_l, nullptr, nullptr, nullptr);
      tcast_k<<<dim3(DD/32, HID/32, NEXP), dim3(32,8), 0, stream>>>(
          w_e2 + (size_t)j*NEXP*HID*DD, wT_big, HID, DD);
      mgemm_t<64><<<dim3(DD/64, NAT), 256, 0, stream>>>(
          hid, wT_big, b_e2 + (size_t)j*NEXP*DD, nullptr, nullptr, nullptr,
          0, DD, HID, F_MOE | F_SCATTER | F_BIAS,
          offs, cnt, tok_l, slot_l, gate_l, moeout);
      combine_k<<<(TT*DD + 255)/256, 256, 0, stream>>>(moeout, h);
    }
  }

  ln_k<<<8, 256, 0, stream>>>(h, (size_t)NTOK*DD, ln_f_g, ln_f_b, clsln, nullptr, 8);
  head_k<<<(BB*NCLS + 255)/256, 256, 0, stream>>>(clsln, w_head, b_head, out);
}

// Round 5
// 1657.637 us; speedup vs baseline: 1.4156x; 1.4156x over previous
//
#include <hip/hip_runtime.h>
#include <math.h>

// ---------------- problem constants ----------------
#define DD 768
#define NHEAD 12
#define HDIM 64
#define NTOK 197
#define BB 8
#define TT (BB*NTOK)          // 1576 tokens
#define NPATCH 196
#define TP (BB*NPATCH)        // 1568 patch rows
#define HID 3072
#define NEXP 8
#define NCLS 1000
#define QKVN (3*DD)           // 2304
#define MAXA 4224             // 33*128 padded MoE capacity (2*TT + 8*127 = 4168)
#define NAT 33                // MoE row tiles of 128
#define NCH 7                 // attention: 7 chunks of 32 cols (224 >= 197)

// epilogue flags
#define F_BIAS    1
#define F_GELU    2
#define F_RESID   4
#define F_OUTBF   8
#define F_MOE     16
#define F_GATHER  32
#define F_SCATTER 64

typedef __bf16 bf16_t;
typedef __attribute__((ext_vector_type(8))) __bf16 bf16x8;
typedef __attribute__((ext_vector_type(4))) float f32x4;

#define GLP(p) ((const __attribute__((address_space(1))) void*)(p))
#define LDP(p) ((__attribute__((address_space(3))) void*)(p))

__device__ __forceinline__ float gelu_f(float x) {
  return 0.5f * x * (1.0f + erff(x * 0.70710678118654752f));
}

// ---------------- transpose+cast: src fp32 [K][N] -> dst bf16 [N][K] ----------------
__global__ void tcast_k(const float* __restrict__ src, bf16_t* __restrict__ dst,
                        int K, int N) {
  src += (size_t)blockIdx.z * K * N;
  dst += (size_t)blockIdx.z * K * N;
  __shared__ float t[32][33];
  int n0 = blockIdx.x * 32, k0 = blockIdx.y * 32;
  int tx = threadIdx.x, ty = threadIdx.y;      // 32 x 8
  #pragma unroll
  for (int i = 0; i < 4; i++)
    t[ty + i*8][tx] = src[(size_t)(k0 + ty + i*8) * N + n0 + tx];
  __syncthreads();
  #pragma unroll
  for (int i = 0; i < 4; i++)
    dst[(size_t)(n0 + ty + i*8) * K + k0 + tx] = (bf16_t)t[tx][ty + i*8];
}

// ---------------- patchify: x[B,3,224,224] -> pm_bf[1568,768] bf16 ----------------
__global__ void patchify_k(const float* __restrict__ x, bf16_t* __restrict__ pm) {
  int idx = blockIdx.x * 256 + threadIdx.x;
  if (idx >= TP * DD) return;
  int cidx = idx % DD;
  int row  = idx / DD;
  int b = row / NPATCH, p = row % NPATCH;
  int c = cidx >> 8;
  int rem = cidx & 255;
  int i = rem >> 4, j = rem & 15;
  int gy = p / 14, gx = p % 14;
  pm[idx] = (bf16_t)x[((size_t)(b*3 + c)*224 + gy*16 + i)*224 + gx*16 + j];
}

// ---------------- assemble h (fp32): cls+pos / tok+pos ----------------
__global__ void assemble_k(const float* __restrict__ tok, const float* __restrict__ cls,
                           const float* __restrict__ pos, float* __restrict__ h) {
  int idx = blockIdx.x * 256 + threadIdx.x;
  if (idx >= TT * DD) return;
  int c = idx % DD;
  int row = idx / DD;
  int b = row / NTOK, n = row % NTOK;
  float v;
  if (n == 0) v = cls[c] + pos[c];
  else        v = tok[((size_t)(b*NPATCH + n - 1))*DD + c] + pos[(size_t)n*DD + c];
  h[idx] = v;
}

// ---------------- layernorm (dual fp32 + optional bf16 out) ----------------
__global__ void ln_k(const float* __restrict__ in, size_t in_stride,
                     const float* __restrict__ g, const float* __restrict__ bta,
                     float* __restrict__ out, bf16_t* __restrict__ out_bf, int nrows) {
  int r = blockIdx.x;
  if (r >= nrows) return;
  const float* xr = in + (size_t)r * in_stride;
  __shared__ float red[256];
  int tid = threadIdx.x;
  float v0 = xr[tid], v1 = xr[tid+256], v2 = xr[tid+512];
  red[tid] = v0 + v1 + v2; __syncthreads();
  for (int st = 128; st > 0; st >>= 1) { if (tid < st) red[tid] += red[tid+st]; __syncthreads(); }
  float mean = red[0] * (1.0f/768.0f); __syncthreads();
  float d0 = v0-mean, d1 = v1-mean, d2 = v2-mean;
  red[tid] = d0*d0 + d1*d1 + d2*d2; __syncthreads();
  for (int st = 128; st > 0; st >>= 1) { if (tid < st) red[tid] += red[tid+st]; __syncthreads(); }
  float rstd = rsqrtf(red[0] * (1.0f/768.0f) + 1e-5f);
  float o0 = d0*rstd*g[tid]     + bta[tid];
  float o1 = d1*rstd*g[tid+256] + bta[tid+256];
  float o2 = d2*rstd*g[tid+512] + bta[tid+512];
  float* o = out + (size_t)r * DD;
  o[tid] = o0; o[tid+256] = o1; o[tid+512] = o2;
  if (out_bf) {
    bf16_t* ob = out_bf + (size_t)r * DD;
    ob[tid] = (bf16_t)o0; ob[tid+256] = (bf16_t)o1; ob[tid+512] = (bf16_t)o2;
  }
}

// ---------------- MFMA GEMM, async global->LDS staging (m97 structure) ----------------
// C[M,N] = epi(A[M,K] @ Bt[N,K]^T). Tile 128 x BN, BK=32.
// LDS layout: blocks of 1024 B; block holds 16 rows as 64 chunks of 16 B ordered
// (kq*16 + r16) == lane order, so global_load_lds (wave-uniform base + lane*16)
// lands each lane's fragment chunk exactly where ds_read_b128 expects it.
// BN=128: 4 waves in 2x2 (acc 4x4). BN=64: 4 waves stacked in m (acc 2x4).
template<int BN>
__global__ __launch_bounds__(256) void mgemm_t(
    const bf16_t* __restrict__ A, const bf16_t* __restrict__ Bt,
    const float* __restrict__ bias, const float* __restrict__ resid,
    float* __restrict__ Cf, bf16_t* __restrict__ Cb,
    int M, int N, int K, int flags,
    const int* __restrict__ offs, const int* __restrict__ cnt,
    const int* __restrict__ tok_l, const int* __restrict__ slot_l,
    const float* __restrict__ gate_l, float* __restrict__ scat_out) {
  constexpr int NB = (BN == 128) ? 2 : 1;   // B row-blocks staged per wave
  constexpr int MI = (BN == 128) ? 4 : 2;   // m-frags per wave
  constexpr int NJ = 4;                     // n-frags per wave
  int row0 = blockIdx.y << 7;
  int col0 = blockIdx.x * BN;
  int vend = M;
  const bf16_t* bt = Bt;
  const float* bs = bias;
  if (flags & F_MOE) {
    int total = offs[NEXP];
    if (row0 >= total) return;
    int e = 0;
    #pragma unroll
    for (int q = 1; q < NEXP; q++) if (row0 >= offs[q]) e = q;
    vend = offs[e] + cnt[e];
    bt = Bt + (size_t)e * N * K;
    bs = bias ? bias + (size_t)e * N : bias;
  }
  int tid = threadIdx.x, wave = tid >> 6, lane = tid & 63;
  int r16 = lane & 15, kq = lane >> 4;
  int kq8 = kq << 3;
  __shared__ bf16_t As[128*32];
  __shared__ bf16_t Bs[BN*32];
  // per-lane global source pointers (row base + lane's k-chunk)
  const bf16_t* ag[2];
  #pragma unroll
  for (int s = 0; s < 2; s++) {
    int gr = row0 + ((wave*2 + s) << 4) + r16;
    if (flags & F_GATHER) {
      int t = (gr < vend) ? tok_l[gr] : 0;
      ag[s] = A + (size_t)t * K + kq8;
    } else {
      int cr = gr; if (cr > vend - 1) cr = vend - 1;
      ag[s] = A + (size_t)cr * K + kq8;
    }
  }
  const bf16_t* bg[NB];
  #pragma unroll
  for (int s = 0; s < NB; s++) {
    int rl = ((wave*NB + s) << 4) + r16;
    bg[s] = bt + (size_t)(col0 + rl) * K + kq8;
  }
  int mi0 = (BN == 128) ? ((wave >> 1) * 4) : (wave * 2);
  int ni0 = (BN == 128) ? ((wave & 1) * 4) : 0;

  f32x4 acc[MI][NJ];
  #pragma unroll
  for (int i = 0; i < MI; i++)
    #pragma unroll
    for (int j = 0; j < NJ; j++)
      acc[i][j] = (f32x4){0.f, 0.f, 0.f, 0.f};

  for (int k0 = 0; k0 < K; k0 += 32) {
    __syncthreads();
    #pragma unroll
    for (int s = 0; s < 2; s++)
      __builtin_amdgcn_global_load_lds(GLP(ag[s] + k0), LDP(&As[(wave*2 + s) * 512]),
                                       16, 0, 0);
    #pragma unroll
    for (int s = 0; s < NB; s++)
      __builtin_amdgcn_global_load_lds(GLP(bg[s] + k0), LDP(&Bs[(wave*NB + s) * 512]),
                                       16, 0, 0);
    __syncthreads();
    bf16x8 af[MI], bfr[NJ];
    #pragma unroll
    for (int i = 0; i < MI; i++) af[i]  = *(const bf16x8*)&As[(mi0+i)*512 + lane*8];
    #pragma unroll
    for (int j = 0; j < NJ; j++) bfr[j] = *(const bf16x8*)&Bs[(ni0+j)*512 + lane*8];
    #pragma unroll
    for (int i = 0; i < MI; i++)
      #pragma unroll
      for (int j = 0; j < NJ; j++)
        acc[i][j] = __builtin_amdgcn_mfma_f32_16x16x32_bf16(af[i], bfr[j], acc[i][j], 0, 0, 0);
  }

  int rq = kq << 2;
  #pragma unroll
  for (int i = 0; i < MI; i++) {
    #pragma unroll
    for (int p = 0; p < 4; p++) {
      int rr = row0 + ((mi0 + i) << 4) + rq + p;
      if (rr >= vend) continue;
      int t = 0, sl = 0; float gv = 0.f;
      if (flags & F_SCATTER) { t = tok_l[rr]; sl = slot_l[rr]; gv = gate_l[rr]; }
      #pragma unroll
      for (int j = 0; j < NJ; j++) {
        int cc = col0 + ((ni0 + j) << 4) + r16;
        float v = acc[i][j][p];
        if (flags & F_BIAS) v += bs[cc];
        if (flags & F_GELU) v = gelu_f(v);
        if (flags & F_SCATTER) {
          scat_out[((size_t)t*2 + sl)*N + cc] = gv * v;
        } else if (flags & F_RESID) {
          Cf[(size_t)rr*N + cc] = v + resid[(size_t)rr*N + cc];
        } else if (flags & F_OUTBF) {
          Cb[(size_t)rr*N + cc] = (bf16_t)v;
        } else {
          Cf[(size_t)rr*N + cc] = v;
        }
      }
    }
  }
}

// ---------------- flash attention: block = (qtile of 64 rows) x (b*head) ----------------
__global__ __launch_bounds__(256) void fattn_k(const bf16_t* __restrict__ qkv,
                                               bf16_t* __restrict__ out) {
  int qt = blockIdx.x;
  int bh = blockIdx.y;
  int b = bh / NHEAD, hh = bh % NHEAD;
  const bf16_t* base = qkv + (size_t)b * NTOK * QKVN;
  int tid = threadIdx.x, wave = tid >> 6, lane = tid & 63;
  int r16 = lane & 15, kq = lane >> 4;

  __shared__ bf16_t Vt[64 * 232];            // V^T [hd][seq], stride 232
  __shared__ bf16_t Ps[4][16 * 40];          // per-wave P scratch, stride 40

  for (int it = 0; it < 56; it++) {
    int idx = it * 256 + tid;
    int d = idx & 63, n = idx >> 6;
    bf16_t bv = (bf16_t)0.f;
    if (n < NTOK) bv = base[(size_t)n * QKVN + 2*DD + hh*HDIM + d];
    Vt[d * 232 + n] = bv;
  }
  __syncthreads();

  int q0 = qt * 64;
  int qrow = q0 + wave * 16 + r16;
  int qr = (qrow < NTOK) ? qrow : 0;
  bf16x8 qf[2];
  #pragma unroll
  for (int ks = 0; ks < 2; ks++)
    qf[ks] = *(const bf16x8*)(base + (size_t)qr * QKVN + hh*HDIM + ks*32 + kq*8);

  f32x4 Oa[4];
  #pragma unroll
  for (int j = 0; j < 4; j++) Oa[j] = (f32x4){0.f,0.f,0.f,0.f};
  float mI[4], lI[4];
  #pragma unroll
  for (int p = 0; p < 4; p++) { mI[p] = -1e30f; lI[p] = 0.f; }

  const bf16_t* Kbase = base + DD + hh*HDIM;
  const bf16x8 zz = {};

  for (int c = 0; c < NCH; c++) {
    f32x4 sc[2];
    sc[0] = (f32x4){0.f,0.f,0.f,0.f};
    sc[1] = (f32x4){0.f,0.f,0.f,0.f};
    #pragma unroll
    for (int tt = 0; tt < 2; tt++) {
      int n = c*32 + tt*16 + r16;
      bool nv = (n < NTOK);
      #pragma unroll
      for (int ks = 0; ks < 2; ks++) {
        bf16x8 kf = zz;
        if (nv) kf = *(const bf16x8*)(Kbase + (size_t)n * QKVN + ks*32 + kq*8);
        sc[tt] = __builtin_amdgcn_mfma_f32_16x16x32_bf16(qf[ks], kf, sc[tt], 0, 0, 0);
      }
    }
    float cm[4];
    #pragma unroll
    for (int p = 0; p < 4; p++) {
      #pragma unroll
      for (int tt = 0; tt < 2; tt++) {
        int col = c*32 + tt*16 + r16;
        float s = sc[tt][p] * 0.125f;
        sc[tt][p] = (col < NTOK) ? s : -1e30f;
      }
      cm[p] = fmaxf(sc[0][p], sc[1][p]);
    }
    #pragma unroll
    for (int off = 1; off < 16; off <<= 1)
      #pragma unroll
      for (int p = 0; p < 4; p++)
        cm[p] = fmaxf(cm[p], __shfl_xor(cm[p], off, 64));
    float al[4], cs[4];
    #pragma unroll
    for (int p = 0; p < 4; p++) {
      float mn = fmaxf(mI[p], cm[p]);
      al[p] = __expf(mI[p] - mn);
      mI[p] = mn;
      float e0 = __expf(sc[0][p] - mn);
      float e1 = __expf(sc[1][p] - mn);
      sc[0][p] = e0; sc[1][p] = e1;
      cs[p] = e0 + e1;
    }
    #pragma unroll
    for (int off = 1; off < 16; off <<= 1)
      #pragma unroll
      for (int p = 0; p < 4; p++)
        cs[p] += __shfl_xor(cs[p], off, 64);
    #pragma unroll
    for (int p = 0; p < 4; p++) lI[p] = lI[p]*al[p] + cs[p];
    #pragma unroll
    for (int j = 0; j < 4; j++)
      #pragma unroll
      for (int p = 0; p < 4; p++)
        Oa[j][p] *= al[p];
    bf16_t* pw = &Ps[wave][0];
    #pragma unroll
    for (int tt = 0; tt < 2; tt++)
      #pragma unroll
      for (int p = 0; p < 4; p++)
        pw[(kq*4+p)*40 + tt*16 + r16] = (bf16_t)sc[tt][p];
    bf16x8 pf = *(const bf16x8*)(pw + r16*40 + kq*8);
    #pragma unroll
    for (int j = 0; j < 4; j++) {
      bf16x8 vf = *(const bf16x8*)(&Vt[(j*16 + r16)*232 + c*32 + kq*8]);
      Oa[j] = __builtin_amdgcn_mfma_f32_16x16x32_bf16(pf, vf, Oa[j], 0, 0, 0);
    }
  }

  #pragma unroll
  for (int p = 0; p < 4; p++) {
    int row = q0 + wave*16 + kq*4 + p;
    if (row >= NTOK) continue;
    float inv = 1.0f / lI[p];
    #pragma unroll
    for (int j = 0; j < 4; j++)
      out[((size_t)b*NTOK + row)*DD + hh*HDIM + j*16 + r16] = (bf16_t)(Oa[j][p] * inv);
  }
}

// ---------------- MoE routing (fp32 gate path) ----------------
__global__ void zero_k(int* __restrict__ cnt) {
  if (threadIdx.x < 16) cnt[threadIdx.x] = 0;
}

__global__ void gate_k(const float* __restrict__ xln, const float* __restrict__ wg,
                       int* __restrict__ e01, float* __restrict__ g01, int* __restrict__ cnt) {
  int t = blockIdx.x * 64 + threadIdx.x;
  if (t >= TT) return;
  float lg[NEXP] = {};
  const float* xr = xln + (size_t)t * DD;
  for (int k = 0; k < DD; k++) {
    float xv = xr[k];
    const float* wr = wg + (size_t)k * NEXP;
    #pragma unroll
    for (int e = 0; e < NEXP; e++) lg[e] += xv * wr[e];
  }
  int e0 = 0; float v0 = lg[0];
  #pragma unroll
  for (int e = 1; e < NEXP; e++) if (lg[e] > v0) { v0 = lg[e]; e0 = e; }
  int e1 = -1; float v1 = -1e30f;
  #pragma unroll
  for (int e = 0; e < NEXP; e++) if (e != e0 && lg[e] > v1) { v1 = lg[e]; e1 = e; }
  float g0 = 1.0f / (1.0f + expf(v1 - v0));
  float g1 = 1.0f - g0;
  e01[t*2]   = e0; e01[t*2+1] = e1;
  g01[t*2]   = g0; g01[t*2+1] = g1;
  atomicAdd(&cnt[e0], 1);
  atomicAdd(&cnt[e1], 1);
}

__global__ void offs_k(const int* __restrict__ cnt, int* __restrict__ offs) {
  if (threadIdx.x == 0 && blockIdx.x == 0) {
    int acc = 0;
    for (int e = 0; e < NEXP; e++) {
      offs[e] = acc;
      acc += ((cnt[e] + 127) >> 7) << 7;
    }
    offs[NEXP] = acc;
  }
}

__global__ void scatter_k(const int* __restrict__ e01, const float* __restrict__ g01,
                          const int* __restrict__ offs, int* __restrict__ cnt2,
                          int* __restrict__ tok_l, float* __restrict__ gate_l,
                          int* __restrict__ slot_l) {
  int t = blockIdx.x * 64 + threadIdx.x;
  if (t >= TT) return;
  #pragma unroll
  for (int s = 0; s < 2; s++) {
    int e = e01[t*2+s];
    int pos = atomicAdd(&cnt2[e], 1);
    int a = offs[e] + pos;
    tok_l[a] = t;
    gate_l[a] = g01[t*2+s];
    slot_l[a] = s;
  }
}

__global__ void combine_k(const float* __restrict__ moe_out, float* __restrict__ h) {
  int idx = blockIdx.x * 256 + threadIdx.x;
  if (idx >= TT * DD) return;
  int c = idx % DD;
  int row = idx / DD;
  h[idx] += moe_out[((size_t)row*2)*DD + c] + moe_out[((size_t)row*2 + 1)*DD + c];
}

// ---------------- head (fp32, small) ----------------
__global__ void head_k(const float* __restrict__ clsln, const float* __restrict__ w_head,
                       const float* __restrict__ b_head, float* __restrict__ out) {
  int id = blockIdx.x * 256 + threadIdx.x;
  if (id >= BB * NCLS) return;
  int b = id / NCLS, c = id % NCLS;
  float acc = b_head[c];
  const float* xr = clsln + (size_t)b * DD;
  for (int k = 0; k < DD; k++) acc += xr[k] * w_head[(size_t)k*NCLS + c];
  out[id] = acc;
}

// ---------------- host ----------------
extern "C" void kernel_launch(void* const* d_in, const int* in_sizes, int n_in,
                              void* d_out, int out_size, void* d_ws, size_t ws_size,
                              hipStream_t stream) {
  const float* x        = (const float*)d_in[0];
  const float* w_patch  = (const float*)d_in[1];
  const float* b_patch  = (const float*)d_in[2];
  const float* cls_tok  = (const float*)d_in[3];
  const float* pos_emb  = (const float*)d_in[4];
  const float* ln1_g    = (const float*)d_in[5];
  const float* ln1_b    = (const float*)d_in[6];
  const float* w_qkv    = (const float*)d_in[7];
  const float* w_proj   = (const float*)d_in[8];
  const float* b_proj   = (const float*)d_in[9];
  const float* ln2_g    = (const float*)d_in[10];
  const float* ln2_b    = (const float*)d_in[11];
  const float* w_fc1    = (const float*)d_in[12];
  const float* b_fc1    = (const float*)d_in[13];
  const float* w_fc2    = (const float*)d_in[14];
  const float* b_fc2    = (const float*)d_in[15];
  const float* w_gate   = (const float*)d_in[16];
  const float* w_e1     = (const float*)d_in[17];
  const float* b_e1     = (const float*)d_in[18];
  const float* w_e2     = (const float*)d_in[19];
  const float* b_e2     = (const float*)d_in[20];
  const float* ln_f_g   = (const float*)d_in[21];
  const float* ln_f_b   = (const float*)d_in[22];
  const float* w_head   = (const float*)d_in[23];
  const float* b_head   = (const float*)d_in[24];
  float* out = (float*)d_out;
  (void)in_sizes; (void)n_in; (void)out_size; (void)ws_size;

  // ---- workspace layout ----
  float* fp = (float*)d_ws;
  float* h      = fp;                          fp += (size_t)TT*DD;
  float* xln    = fp;                          fp += (size_t)TT*DD;
  float* moeout = fp;                          fp += (size_t)TT*2*DD;
  float* clsln  = fp;                          fp += (size_t)8*DD;
  float* g01    = fp;                          fp += (size_t)TT*2;
  float* gate_l = fp;                          fp += (size_t)MAXA;
  int* ip = (int*)fp;
  int* e01    = ip;                            ip += TT*2;
  int* cnt    = ip;                            ip += 8;
  int* cnt2   = ip;                            ip += 8;
  int* offs   = ip;                            ip += 16;
  int* tok_l  = ip;                            ip += MAXA;
  int* slot_l = ip;                            ip += MAXA;
  bf16_t* bp = (bf16_t*)ip;
  bf16_t* pm_bf   = bp;                        bp += (size_t)TP*DD;
  bf16_t* xln_bf  = bp;                        bp += (size_t)TT*DD;
  bf16_t* qkv_bf  = bp;                        bp += (size_t)TT*QKVN;
  bf16_t* attnb   = bp;                        bp += (size_t)TT*DD;
  bf16_t* hid     = bp;                        bp += (size_t)MAXA*HID;
  bf16_t* wT_patch= bp;                        bp += (size_t)DD*DD;
  bf16_t* wT_qkv  = bp;                        bp += (size_t)DD*QKVN;
  bf16_t* wT_proj = bp;                        bp += (size_t)DD*DD;
  bf16_t* wT_big  = bp;                        bp += (size_t)NEXP*DD*HID;

  // ---- patch embedding ----
  tcast_k<<<dim3(DD/32, DD/32, 1), dim3(32,8), 0, stream>>>(w_patch, wT_patch, DD, DD);
  patchify_k<<<(TP*DD + 255)/256, 256, 0, stream>>>(x, pm_bf);
  mgemm_t<64><<<dim3(DD/64, (TP+127)/128), 256, 0, stream>>>(
      pm_bf, wT_patch, b_patch, nullptr, xln, nullptr, TP, DD, DD, F_BIAS,
      nullptr, nullptr, nullptr, nullptr, nullptr, nullptr);
  assemble_k<<<(TT*DD + 255)/256, 256, 0, stream>>>(xln, cls_tok, pos_emb, h);

  const int MT = (TT + 127) / 128;   // 13 row tiles
  for (int i = 0; i < 4; i++) {
    int j = i >> 1;
    // attention
    tcast_k<<<dim3(QKVN/32, DD/32, 1), dim3(32,8), 0, stream>>>(
        w_qkv + (size_t)i*DD*QKVN, wT_qkv, DD, QKVN);
    tcast_k<<<dim3(DD/32, DD/32, 1), dim3(32,8), 0, stream>>>(
        w_proj + (size_t)i*DD*DD, wT_proj, DD, DD);
    ln_k<<<TT, 256, 0, stream>>>(h, DD, ln1_g + (size_t)i*DD, ln1_b + (size_t)i*DD,
                                 xln, xln_bf, TT);
    mgemm_t<128><<<dim3(QKVN/128, MT), 256, 0, stream>>>(
        xln_bf, wT_qkv, nullptr, nullptr, nullptr, qkv_bf, TT, QKVN, DD, F_OUTBF,
        nullptr, nullptr, nullptr, nullptr, nullptr, nullptr);
    fattn_k<<<dim3(4, BB*NHEAD), 256, 0, stream>>>(qkv_bf, attnb);
    mgemm_t<64><<<dim3(DD/64, MT), 256, 0, stream>>>(
        attnb, wT_proj, b_proj + (size_t)i*DD, h, h, nullptr, TT, DD, DD,
        F_BIAS | F_RESID, nullptr, nullptr, nullptr, nullptr, nullptr, nullptr);
    // mlp / moe
    ln_k<<<TT, 256, 0, stream>>>(h, DD, ln2_g + (size_t)i*DD, ln2_b + (size_t)i*DD,
                                 xln, xln_bf, TT);
    if ((i & 1) == 0) {
      tcast_k<<<dim3(HID/32, DD/32, 1), dim3(32,8), 0, stream>>>(
          w_fc1 + (size_t)j*DD*HID, wT_big, DD, HID);
      mgemm_t<128><<<dim3(HID/128, MT), 256, 0, stream>>>(
          xln_bf, wT_big, b_fc1 + (size_t)j*HID, nullptr, nullptr, hid,
          TT, HID, DD, F_BIAS | F_GELU | F_OUTBF,
          nullptr, nullptr, nullptr, nullptr, nullptr, nullptr);
      tcast_k<<<dim3(DD/32, HID/32, 1), dim3(32,8), 0, stream>>>(
          w_fc2 + (size_t)j*HID*DD, wT_big, HID, DD);
      mgemm_t<64><<<dim3(DD/64, MT), 256, 0, stream>>>(
          hid, wT_big, b_fc2 + (size_t)j*DD, h, h, nullptr, TT, DD, HID,
          F_BIAS | F_RESID, nullptr, nullptr, nullptr, nullptr, nullptr, nullptr);
    } else {
      zero_k<<<1, 64, 0, stream>>>(cnt);
      gate_k<<<(TT+63)/64, 64, 0, stream>>>(xln, w_gate + (size_t)j*DD*NEXP, e01, g01, cnt);
      offs_k<<<1, 32, 0, stream>>>(cnt, offs);
      scatter_k<<<(TT+63)/64, 64, 0, stream>>>(e01, g01, offs, cnt2, tok_l, gate_l, slot_l);
      tcast_k<<<dim3(HID/32, DD/32, NEXP), dim3(32,8), 0, stream>>>(
          w_e1 + (size_t)j*NEXP*DD*HID, wT_big, DD, HID);
      mgemm_t<128><<<dim3(HID/128, NAT), 256, 0, stream>>>(
          xln_bf, wT_big, b_e1 + (size_t)j*NEXP*HID, nullptr, nullptr, hid,
          0, HID, DD, F_MOE | F_GATHER | F_BIAS | F_GELU | F_OUTBF,
          offs, cnt, tok_l, nullptr, nullptr, nullptr);
      tcast_k<<<dim3(DD/32, HID/32, NEXP), dim3(32,8), 0, stream>>>(
          w_e2 + (size_t)j*NEXP*HID*DD, wT_big, HID, DD);
      mgemm_t<64><<<dim3(DD/64, NAT), 256, 0, stream>>>(
          hid, wT_big, b_e2 + (size_t)j*NEXP*DD, nullptr, nullptr, nullptr,
          0, DD, HID, F_MOE | F_SCATTER | F_BIAS,
          offs, cnt, tok_l, slot_l, gate_l, moeout);
      combine_k<<<(TT*DD + 255)/256, 256, 0, stream>>>(moeout, h);
    }
  }

  ln_k<<<8, 256, 0, stream>>>(h, (size_t)NTOK*DD, ln_f_g, ln_f_b, clsln, nullptr, 8);
  head_k<<<(BB*NCLS + 255)/256, 256, 0, stream>>>(clsln, w_head, b_head, out);
}